// Round 5
// baseline (694.970 us; speedup 1.0000x reference)
//
#include <hip/hip_runtime.h>
#include <hip/hip_bf16.h>
#include <cstdio>

#define NTOK 4096
#define DDIM 1024
#define HDIM 2048
#define NEXP 16
#define NPAIR (NTOK * 3)
#define BM 128
#define MAXT1 112
#define MAXT2 112

typedef __bf16 bf16x8 __attribute__((ext_vector_type(8)));
typedef float f32x4 __attribute__((ext_vector_type(4)));
typedef unsigned short ushort8v __attribute__((ext_vector_type(8)));

// ---------- ws byte layout ----------
// meta ints @0 (counts@0, offs@16, cursor@48, nt@64, tile_e@128, tile_r0@256)
#define OFF_TOPKE 4096
#define OFF_TOPKW 53248
#define OFF_PERM 102400
#define OFF_PW 151552
#define OFF_XB 262144              // fast: bf16 x [4096][1024] (8 MB)
#define OFF_HID_F 8650752          // fast: bf16 hidden [12288][2048] (48 MB)
#define OFF_W1T 58982400           // fast: bf16 W1 tiled (64 MB)
#define OFF_W2T 126091264          // fast: bf16 W2 tiled (64 MB)
#define NEED_FAST 193200128ull
#define OFF_HID_S 262144           // slow fallback: hidden at 256 KB
#define NEED_SLOW 50593792ull

__device__ __forceinline__ unsigned short f2bf(float f) {
    __bf16 h = (__bf16)f;
    return __builtin_bit_cast(unsigned short, h);
}

typedef const __attribute__((address_space(1))) unsigned int* as1_u32p;
typedef __attribute__((address_space(3))) unsigned int* as3_u32p;
__device__ __forceinline__ void gload16(const void* g, void* l) {
    __builtin_amdgcn_global_load_lds((as1_u32p)g, (as3_u32p)l, 16, 0, 0);
}

// ================= gating (+ optional x->bf16 convert) =================
__global__ void k_gating(const float* __restrict__ x, const float* __restrict__ gate,
                         int* __restrict__ topk_e, float* __restrict__ topk_w,
                         int* __restrict__ counts, unsigned short* __restrict__ xb) {
    const int t = blockIdx.x;
    const int l = threadIdx.x;
    const int e = l & 15, grp = l >> 4;
    const float* xr = x + (size_t)t * DDIM;
    double s = 0.0;
    const int d0 = grp * 256;
    for (int d = d0; d < d0 + 256; d += 4) {
        float4 xv = *(const float4*)(xr + d);
        if (xb && e == 0) {
            ushort4 pk;
            pk.x = f2bf(xv.x); pk.y = f2bf(xv.y); pk.z = f2bf(xv.z); pk.w = f2bf(xv.w);
            *(ushort4*)&xb[(size_t)t * DDIM + d] = pk;
        }
        s += (double)xv.x * (double)gate[(d + 0) * NEXP + e];
        s += (double)xv.y * (double)gate[(d + 1) * NEXP + e];
        s += (double)xv.z * (double)gate[(d + 2) * NEXP + e];
        s += (double)xv.w * (double)gate[(d + 3) * NEXP + e];
    }
    s += __shfl_xor(s, 16);
    s += __shfl_xor(s, 32);
    // top-3 on double logits (softmax monotone); lowest index wins ties
    double cur = s;
    double lsel[3];
    int esel[3];
#pragma unroll
    for (int j = 0; j < 3; ++j) {
        double mx = cur;
#pragma unroll
        for (int off = 8; off >= 1; off >>= 1) {
            double o = __shfl_xor(mx, off);
            mx = (o > mx) ? o : mx;
        }
        unsigned long long b = __ballot(cur == mx);
        int sel = (__ffsll(b) - 1) & 15;
        esel[j] = sel;
        lsel[j] = mx;
        if (e == sel) cur = -1.0e300;
    }
    float w0 = 1.0f;
    float w1 = expf((float)(lsel[1] - lsel[0]));
    float w2 = expf((float)(lsel[2] - lsel[0]));
    float inv = 1.0f / (w0 + w1 + w2);
    if (l < 3) {
        float wv = (l == 0) ? w0 : (l == 1) ? w1 : w2;
        topk_e[t * 3 + l] = esel[l];
        topk_w[t * 3 + l] = wv * inv;
        atomicAdd(&counts[esel[l]], 1);
    }
}

__global__ void k_scan(int* __restrict__ meta) {
    if (threadIdx.x != 0) return;
    int* counts = meta;
    int* offs = meta + 16;
    int* cursor = meta + 48;
    int acc = 0;
    for (int e = 0; e < NEXP; ++e) {
        offs[e] = acc;
        cursor[e] = acc;
        acc += counts[e];
    }
    offs[NEXP] = acc;
    int nt = 0;
    for (int e = 0; e < NEXP; ++e)
        for (int r = offs[e]; r < offs[e + 1]; r += BM) {
            meta[128 + nt] = e;
            meta[256 + nt] = r;
            ++nt;
        }
    meta[64] = nt;
}

__global__ void k_scatter(const int* __restrict__ topk_e, const float* __restrict__ topk_w,
                          int* __restrict__ cursor, int* __restrict__ perm,
                          float* __restrict__ pw) {
    int t = blockIdx.x * blockDim.x + threadIdx.x;
    if (t >= NTOK) return;
#pragma unroll
    for (int j = 0; j < 3; ++j) {
        int e = topk_e[t * 3 + j];
        int pos = atomicAdd(&cursor[e], 1);
        perm[pos] = t;
        pw[pos] = topk_w[t * 3 + j];
    }
}

// ====== weight convert: W[e][K][N] fp32 -> tiled bf16, transposed + swizzled ======
// out tile (e,nt,kt): 512 chunks of 16B; chunk (r,c) holds k-chunk cs=c^((r>>1)&3):
//   elem i = bf16( W[e][kt*32 + 8*cs + i][nt*128 + r] )
template <int K, int N, int NTILES, int KTILES>
__global__ __launch_bounds__(256) void k_convW(const float* __restrict__ W,
                                               unsigned short* __restrict__ Wt) {
    __shared__ unsigned short Ls[32 * 132];
    const int b = blockIdx.x;
    const int kt = b % KTILES;
    const int nt = (b / KTILES) % NTILES;
    const int e = b / (KTILES * NTILES);
    const int tid = threadIdx.x;
#pragma unroll
    for (int q = 0; q < 4; ++q) {
        int idx = q * 256 + tid;  // 0..1023 : 32 k x 32 h-groups
        int k = idx >> 5, hg = idx & 31;
        const float* src = W + ((size_t)e * K + kt * 32 + k) * N + nt * 128 + hg * 4;
        float4 v = *(const float4*)src;
        ushort4 pk;
        pk.x = f2bf(v.x); pk.y = f2bf(v.y); pk.z = f2bf(v.z); pk.w = f2bf(v.w);
        *(ushort4*)&Ls[k * 132 + hg * 4] = pk;
    }
    __syncthreads();
    unsigned short* outb = Wt + (size_t)b * 4096;  // 8 KB tile
#pragma unroll
    for (int q = 0; q < 2; ++q) {
        int cidx = q * 256 + tid;  // 0..511
        int r = cidx >> 2, c = cidx & 3;
        int cs = c ^ ((r >> 1) & 3);
        ushort8v v;
#pragma unroll
        for (int i = 0; i < 8; ++i) v[i] = Ls[(8 * cs + i) * 132 + r];
        *(ushort8v*)&outb[cidx * 8] = v;
    }
}

// ========== fast GEMMs: 2-phase double-buffered global_load_lds pipeline ==========
// LDS image per buffer: row r (64B of 32 bf16 k-values), 16B-chunk c holds
// k-chunk c^((r>>1)&3). Iteration t: stage tile t+1 into buf^1 (loads in
// flight during compute of tile t from buf); the single trailing
// __syncthreads() drains vmcnt AFTER compute, overlapping HBM latency.
__global__ __launch_bounds__(256) void k_gemm1_f(const unsigned short* __restrict__ xb,
                                                 const unsigned short* __restrict__ W1t,
                                                 const float* __restrict__ b1,
                                                 const int* __restrict__ meta,
                                                 const int* __restrict__ perm,
                                                 unsigned short* __restrict__ hidden) {
    const int b = blockIdx.x;
    const int wg = (b & 7) * 224 + (b >> 3);  // XCD-contiguous chunks (1792 = 8*224)
    const int mt = wg % MAXT1;
    const int y = wg / MAXT1;  // h-tile 0..15
    if (mt >= meta[64]) return;
    const int e = meta[128 + mt];
    const int r0 = meta[256 + mt];
    const int limit = meta[16 + e + 1] - r0;

    __shared__ unsigned short As_l[2][4096];
    __shared__ unsigned short Bs_l[2][4096];

    const int tid = threadIdx.x;
    const int lane = tid & 63, wave = tid >> 6;
    const int wr = wave >> 1, wc = wave & 1;

    // hoisted per-lane staging bases
    size_t abase[2];
    size_t bbase[2];
#pragma unroll
    for (int q = 0; q < 2; ++q) {
        int cidx = q * 256 + tid;
        int r = cidx >> 2, c = cidx & 3;
        int cs = c ^ ((r >> 1) & 3);
        int rr = r0 + r; if (rr > NPAIR - 1) rr = NPAIR - 1;
        abase[q] = (size_t)perm[rr] * (DDIM * 2) + (size_t)cs * 16;
        bbase[q] = ((size_t)((e * 16 + y) * 32)) * 8192 + (size_t)cidx * 16;
    }
    const char* xb_b = (const char*)xb;
    const char* w_b = (const char*)W1t;

    f32x4 acc[4][4];
#pragma unroll
    for (int i = 0; i < 4; ++i)
#pragma unroll
        for (int j = 0; j < 4; ++j) acc[i][j] = (f32x4){0.f, 0.f, 0.f, 0.f};

    const int NKT = DDIM / 32;
    // prologue: stage tile 0 into buf 0, full drain
#pragma unroll
    for (int q = 0; q < 2; ++q) {
        gload16(xb_b + abase[q], &As_l[0][(q * 256 + wave * 64) * 8]);
        gload16(w_b + bbase[q], &Bs_l[0][(q * 256 + wave * 64) * 8]);
    }
    __syncthreads();

    for (int kt = 0; kt < NKT; ++kt) {
        const int cur = kt & 1;
        if (kt + 1 < NKT) {
#pragma unroll
            for (int q = 0; q < 2; ++q) {
                gload16(xb_b + abase[q] + (size_t)(kt + 1) * 64,
                        &As_l[cur ^ 1][(q * 256 + wave * 64) * 8]);
                gload16(w_b + bbase[q] + (size_t)(kt + 1) * 8192,
                        &Bs_l[cur ^ 1][(q * 256 + wave * 64) * 8]);
            }
        }
        bf16x8 af[4], bfr[4];
#pragma unroll
        for (int m = 0; m < 4; ++m) {
            int r = wr * 64 + m * 16 + (lane & 15);
            int cc = ((lane >> 4) ^ ((r >> 1) & 3)) * 8;
            af[m] = *(const bf16x8*)&As_l[cur][r * 32 + cc];
        }
#pragma unroll
        for (int n = 0; n < 4; ++n) {
            int r = wc * 64 + n * 16 + (lane & 15);
            int cc = ((lane >> 4) ^ ((r >> 1) & 3)) * 8;
            bfr[n] = *(const bf16x8*)&Bs_l[cur][r * 32 + cc];
        }
#pragma unroll
        for (int m = 0; m < 4; ++m)
#pragma unroll
            for (int n = 0; n < 4; ++n)
                acc[m][n] = __builtin_amdgcn_mfma_f32_16x16x32_bf16(af[m], bfr[n], acc[m][n], 0, 0, 0);
        // single barrier: drains vmcnt(0) AFTER compute (next tile ready),
        // and fences readers of buf[cur^1] before it is overwritten.
        __syncthreads();
    }

    const int h0 = y * 128;
    float bias[4];
#pragma unroll
    for (int n = 0; n < 4; ++n)
        bias[n] = b1[(size_t)e * HDIM + h0 + wc * 64 + n * 16 + (lane & 15)];
#pragma unroll
    for (int m = 0; m < 4; ++m)
#pragma unroll
        for (int j = 0; j < 4; ++j) {
            int row = wr * 64 + m * 16 + (lane >> 4) * 4 + j;
            if (row < limit) {
                size_t base = (size_t)(r0 + row) * HDIM + h0;
#pragma unroll
                for (int n = 0; n < 4; ++n) {
                    int col = wc * 64 + n * 16 + (lane & 15);
                    float v = acc[m][n][j] + bias[n];
                    hidden[base + col] = f2bf(fmaxf(v, 0.f));
                }
            }
        }
}

__global__ __launch_bounds__(256) void k_gemm2_f(const unsigned short* __restrict__ hidden,
                                                 const unsigned short* __restrict__ W2t,
                                                 const float* __restrict__ b2,
                                                 const int* __restrict__ meta,
                                                 const int* __restrict__ perm,
                                                 const float* __restrict__ pw,
                                                 float* __restrict__ out) {
    const int b = blockIdx.x;
    const int wg = (b & 7) * 112 + (b >> 3);  // 896 = 8*112
    const int mt = wg % MAXT2;
    const int y = wg / MAXT2;  // d-tile 0..7
    if (mt >= meta[64]) return;
    const int e = meta[128 + mt];
    const int r0 = meta[256 + mt];
    const int limit = meta[16 + e + 1] - r0;

    __shared__ unsigned short As_l[2][4096];
    __shared__ unsigned short Bs_l[2][4096];

    const int tid = threadIdx.x;
    const int lane = tid & 63, wave = tid >> 6;
    const int wr = wave >> 1, wc = wave & 1;

    size_t abase[2];
    size_t bbase[2];
#pragma unroll
    for (int q = 0; q < 2; ++q) {
        int cidx = q * 256 + tid;
        int r = cidx >> 2, c = cidx & 3;
        int cs = c ^ ((r >> 1) & 3);
        int rr = r0 + r; if (rr > NPAIR - 1) rr = NPAIR - 1;
        abase[q] = (size_t)rr * (HDIM * 2) + (size_t)cs * 16;
        bbase[q] = ((size_t)((e * 8 + y) * 64)) * 8192 + (size_t)cidx * 16;
    }
    const char* h_b = (const char*)hidden;
    const char* w_b = (const char*)W2t;

    f32x4 acc[4][4];
#pragma unroll
    for (int i = 0; i < 4; ++i)
#pragma unroll
        for (int j = 0; j < 4; ++j) acc[i][j] = (f32x4){0.f, 0.f, 0.f, 0.f};

    const int NKT = HDIM / 32;
#pragma unroll
    for (int q = 0; q < 2; ++q) {
        gload16(h_b + abase[q], &As_l[0][(q * 256 + wave * 64) * 8]);
        gload16(w_b + bbase[q], &Bs_l[0][(q * 256 + wave * 64) * 8]);
    }
    __syncthreads();

    for (int kt = 0; kt < NKT; ++kt) {
        const int cur = kt & 1;
        if (kt + 1 < NKT) {
#pragma unroll
            for (int q = 0; q < 2; ++q) {
                gload16(h_b + abase[q] + (size_t)(kt + 1) * 64,
                        &As_l[cur ^ 1][(q * 256 + wave * 64) * 8]);
                gload16(w_b + bbase[q] + (size_t)(kt + 1) * 8192,
                        &Bs_l[cur ^ 1][(q * 256 + wave * 64) * 8]);
            }
        }
        bf16x8 af[4], bfr[4];
#pragma unroll
        for (int m = 0; m < 4; ++m) {
            int r = wr * 64 + m * 16 + (lane & 15);
            int cc = ((lane >> 4) ^ ((r >> 1) & 3)) * 8;
            af[m] = *(const bf16x8*)&As_l[cur][r * 32 + cc];
        }
#pragma unroll
        for (int n = 0; n < 4; ++n) {
            int r = wc * 64 + n * 16 + (lane & 15);
            int cc = ((lane >> 4) ^ ((r >> 1) & 3)) * 8;
            bfr[n] = *(const bf16x8*)&Bs_l[cur][r * 32 + cc];
        }
#pragma unroll
        for (int m = 0; m < 4; ++m)
#pragma unroll
            for (int n = 0; n < 4; ++n)
                acc[m][n] = __builtin_amdgcn_mfma_f32_16x16x32_bf16(af[m], bfr[n], acc[m][n], 0, 0, 0);
        __syncthreads();
    }

    const int n0 = y * 128;
    float bias[4];
#pragma unroll
    for (int n = 0; n < 4; ++n)
        bias[n] = b2[(size_t)e * DDIM + n0 + wc * 64 + n * 16 + (lane & 15)];
#pragma unroll
    for (int m = 0; m < 4; ++m)
#pragma unroll
        for (int j = 0; j < 4; ++j) {
            int row = wr * 64 + m * 16 + (lane >> 4) * 4 + j;
            if (row < limit) {
                int tok = perm[r0 + row];
                float w = pw[r0 + row];
#pragma unroll
                for (int n = 0; n < 4; ++n) {
                    int col = wc * 64 + n * 16 + (lane & 15);
                    float v = (acc[m][n][j] + bias[n]) * w;
                    atomicAdd(&out[(size_t)tok * DDIM + n0 + col], v);
                }
            }
        }
}

// ================= slow fallback GEMMs (round-2, verified) =================
__global__ __launch_bounds__(256) void k_gemm1_s(const float* __restrict__ x,
                                                 const float* __restrict__ W1,
                                                 const float* __restrict__ b1,
                                                 const int* __restrict__ meta,
                                                 const int* __restrict__ perm,
                                                 unsigned short* __restrict__ hidden) {
    const int mt = blockIdx.x;
    if (mt >= meta[64]) return;
    const int e = meta[128 + mt];
    const int r0 = meta[256 + mt];
    const int limit = meta[16 + e + 1] - r0;
    const int h0 = blockIdx.y * 128;

    __shared__ unsigned short As[128][40];
    __shared__ unsigned short Bs[128][40];

    const int tid = threadIdx.x;
    const int lane = tid & 63, wave = tid >> 6;
    const int wr = wave >> 1, wc = wave & 1;
    const int arow = tid >> 1, ahalf = tid & 1;
    const float* aptr = nullptr;
    if (arow < limit) aptr = x + (size_t)perm[r0 + arow] * DDIM + ahalf * 16;

    f32x4 acc[4][4];
#pragma unroll
    for (int i = 0; i < 4; ++i)
#pragma unroll
        for (int j = 0; j < 4; ++j) acc[i][j] = (f32x4){0.f, 0.f, 0.f, 0.f};

    for (int k0 = 0; k0 < DDIM; k0 += 32) {
        __syncthreads();
#pragma unroll
        for (int i = 0; i < 4; ++i) {
            float4 v = make_float4(0.f, 0.f, 0.f, 0.f);
            if (aptr) v = *(const float4*)(aptr + k0 + i * 4);
            ushort4 pk;
            pk.x = f2bf(v.x); pk.y = f2bf(v.y); pk.z = f2bf(v.z); pk.w = f2bf(v.w);
            *(ushort4*)&As[arow][ahalf * 16 + i * 4] = pk;
        }
#pragma unroll
        for (int it = 0; it < 2; ++it) {
            int s = tid + it * 256;
            int kp = s >> 5, cg = s & 31;
            const float* bp = W1 + ((size_t)e * DDIM + k0 + 2 * kp) * HDIM + h0 + cg * 4;
            float4 v0 = *(const float4*)bp;
            float4 v1 = *(const float4*)(bp + HDIM);
#pragma unroll
            for (int c = 0; c < 4; ++c) {
                unsigned int u = ((unsigned)f2bf(((const float*)&v1)[c]) << 16) |
                                 f2bf(((const float*)&v0)[c]);
                *(unsigned int*)&Bs[cg * 4 + c][2 * kp] = u;
            }
        }
        __syncthreads();
        bf16x8 af[4], bfr[4];
#pragma unroll
        for (int m = 0; m < 4; ++m)
            af[m] = *(const bf16x8*)&As[wr * 64 + m * 16 + (lane & 15)][(lane >> 4) * 8];
#pragma unroll
        for (int n = 0; n < 4; ++n)
            bfr[n] = *(const bf16x8*)&Bs[wc * 64 + n * 16 + (lane & 15)][(lane >> 4) * 8];
#pragma unroll
        for (int m = 0; m < 4; ++m)
#pragma unroll
            for (int n = 0; n < 4; ++n)
                acc[m][n] = __builtin_amdgcn_mfma_f32_16x16x32_bf16(af[m], bfr[n], acc[m][n], 0, 0, 0);
    }

    float bias[4];
#pragma unroll
    for (int n = 0; n < 4; ++n)
        bias[n] = b1[(size_t)e * HDIM + h0 + wc * 64 + n * 16 + (lane & 15)];
#pragma unroll
    for (int m = 0; m < 4; ++m)
#pragma unroll
        for (int j = 0; j < 4; ++j) {
            int row = wr * 64 + m * 16 + (lane >> 4) * 4 + j;
            if (row < limit) {
                size_t base = (size_t)(r0 + row) * HDIM + h0;
#pragma unroll
                for (int n = 0; n < 4; ++n) {
                    int col = wc * 64 + n * 16 + (lane & 15);
                    float v = acc[m][n][j] + bias[n];
                    hidden[base + col] = f2bf(fmaxf(v, 0.f));
                }
            }
        }
}

__global__ __launch_bounds__(256) void k_gemm2_s(const unsigned short* __restrict__ hidden,
                                                 const float* __restrict__ W2,
                                                 const float* __restrict__ b2,
                                                 const int* __restrict__ meta,
                                                 const int* __restrict__ perm,
                                                 const float* __restrict__ pw,
                                                 float* __restrict__ out) {
    const int mt = blockIdx.x;
    if (mt >= meta[64]) return;
    const int e = meta[128 + mt];
    const int r0 = meta[256 + mt];
    const int limit = meta[16 + e + 1] - r0;
    const int n0 = blockIdx.y * 128;

    __shared__ unsigned short As[128][40];
    __shared__ unsigned short Bs[128][40];

    const int tid = threadIdx.x;
    const int lane = tid & 63, wave = tid >> 6;
    const int wr = wave >> 1, wc = wave & 1;
    const int arow = tid >> 1, ahalf = tid & 1;
    const unsigned short* aptr = nullptr;
    if (arow < limit) aptr = hidden + (size_t)(r0 + arow) * HDIM + ahalf * 16;

    f32x4 acc[4][4];
#pragma unroll
    for (int i = 0; i < 4; ++i)
#pragma unroll
        for (int j = 0; j < 4; ++j) acc[i][j] = (f32x4){0.f, 0.f, 0.f, 0.f};

    for (int k0 = 0; k0 < HDIM; k0 += 32) {
        __syncthreads();
#pragma unroll
        for (int i = 0; i < 2; ++i) {
            uint4 v = make_uint4(0u, 0u, 0u, 0u);
            if (aptr) v = *(const uint4*)(aptr + k0 + i * 8);
            *(uint4*)&As[arow][ahalf * 16 + i * 8] = v;
        }
#pragma unroll
        for (int it = 0; it < 2; ++it) {
            int s = tid + it * 256;
            int kp = s >> 5, cg = s & 31;
            const float* bp = W2 + ((size_t)e * HDIM + k0 + 2 * kp) * DDIM + n0 + cg * 4;
            float4 v0 = *(const float4*)bp;
            float4 v1 = *(const float4*)(bp + DDIM);
#pragma unroll
            for (int c = 0; c < 4; ++c) {
                unsigned int u = ((unsigned)f2bf(((const float*)&v1)[c]) << 16) |
                                 f2bf(((const float*)&v0)[c]);
                *(unsigned int*)&Bs[cg * 4 + c][2 * kp] = u;
            }
        }
        __syncthreads();
        bf16x8 af[4], bfr[4];
#pragma unroll
        for (int m = 0; m < 4; ++m)
            af[m] = *(const bf16x8*)&As[wr * 64 + m * 16 + (lane & 15)][(lane >> 4) * 8];
#pragma unroll
        for (int n = 0; n < 4; ++n)
            bfr[n] = *(const bf16x8*)&Bs[wc * 64 + n * 16 + (lane & 15)][(lane >> 4) * 8];
#pragma unroll
        for (int m = 0; m < 4; ++m)
#pragma unroll
            for (int n = 0; n < 4; ++n)
                acc[m][n] = __builtin_amdgcn_mfma_f32_16x16x32_bf16(af[m], bfr[n], acc[m][n], 0, 0, 0);
    }

    float bias[4];
#pragma unroll
    for (int n = 0; n < 4; ++n)
        bias[n] = b2[(size_t)e * DDIM + n0 + wc * 64 + n * 16 + (lane & 15)];
#pragma unroll
    for (int m = 0; m < 4; ++m)
#pragma unroll
        for (int j = 0; j < 4; ++j) {
            int row = wr * 64 + m * 16 + (lane >> 4) * 4 + j;
            if (row < limit) {
                int tok = perm[r0 + row];
                float w = pw[r0 + row];
#pragma unroll
                for (int n = 0; n < 4; ++n) {
                    int col = wc * 64 + n * 16 + (lane & 15);
                    float v = (acc[m][n][j] + bias[n]) * w;
                    atomicAdd(&out[(size_t)tok * DDIM + n0 + col], v);
                }
            }
        }
}

extern "C" void kernel_launch(void* const* d_in, const int* in_sizes, int n_in,
                              void* d_out, int out_size, void* d_ws, size_t ws_size,
                              hipStream_t stream) {
    const float* x = (const float*)d_in[0];
    const float* gate = (const float*)d_in[1];
    const float* W1 = (const float*)d_in[2];
    const float* b1 = (const float*)d_in[3];
    const float* W2 = (const float*)d_in[4];
    const float* b2 = (const float*)d_in[5];
    float* out = (float*)d_out;

    const bool fast = ws_size >= NEED_FAST;
    if (!fast && ws_size < NEED_SLOW) {
        fprintf(stderr, "SparseKMoE: ws_size %zu too small\n", ws_size);
        return;
    }
    char* ws = (char*)d_ws;
    int* meta = (int*)ws;
    int* topk_e = (int*)(ws + OFF_TOPKE);
    float* topk_w = (float*)(ws + OFF_TOPKW);
    int* perm = (int*)(ws + OFF_PERM);
    float* pw = (float*)(ws + OFF_PW);
    unsigned short* xb = (unsigned short*)(ws + OFF_XB);
    unsigned short* hidden = (unsigned short*)(ws + (fast ? OFF_HID_F : OFF_HID_S));
    unsigned short* W1t = (unsigned short*)(ws + OFF_W1T);
    unsigned short* W2t = (unsigned short*)(ws + OFF_W2T);

    hipMemsetAsync(meta, 0, 4096, stream);
    hipMemsetAsync(d_out, 0, (size_t)NTOK * DDIM * sizeof(float), stream);

    k_gating<<<NTOK, 64, 0, stream>>>(x, gate, topk_e, topk_w, meta, fast ? xb : nullptr);
    k_scan<<<1, 64, 0, stream>>>(meta);
    k_scatter<<<16, 256, 0, stream>>>(topk_e, topk_w, meta + 48, perm, pw);

    if (fast) {
        k_convW<DDIM, HDIM, 16, 32><<<NEXP * 16 * 32, 256, 0, stream>>>(W1, W1t);
        k_convW<HDIM, DDIM, 8, 64><<<NEXP * 8 * 64, 256, 0, stream>>>(W2, W2t);
        k_gemm1_f<<<MAXT1 * 16, 256, 0, stream>>>(xb, W1t, b1, meta, perm, hidden);
        k_gemm2_f<<<MAXT2 * 8, 256, 0, stream>>>(hidden, W2t, b2, meta, perm, pw, out);
    } else {
        dim3 g1(MAXT1, HDIM / 128);
        k_gemm1_s<<<g1, 256, 0, stream>>>(x, W1, b1, meta, perm, hidden);
        dim3 g2(MAXT2, DDIM / 128);
        k_gemm2_s<<<g2, 256, 0, stream>>>(hidden, W2, b2, meta, perm, pw, out);
    }
}

// Round 7
// 651.769 us; speedup vs baseline: 1.0663x; 1.0663x over previous
//
#include <hip/hip_runtime.h>
#include <hip/hip_bf16.h>
#include <cstdio>

#define NTOK 4096
#define DDIM 1024
#define HDIM 2048
#define NEXP 16
#define NPAIR (NTOK * 3)
#define BM 128
#define MAXT1 112
#define MAXT2 112

typedef __bf16 bf16x8 __attribute__((ext_vector_type(8)));
typedef float f32x4 __attribute__((ext_vector_type(4)));
typedef unsigned short ushort8v __attribute__((ext_vector_type(8)));

// ---------- ws byte layout ----------
// meta ints @0 (counts@0, offs@16, cursor@48, nt@64, tile_e@128, tile_r0@256)
#define OFF_TOPKE 4096
#define OFF_TOPKW 53248
#define OFF_PERM 102400
#define OFF_PW 151552
#define OFF_XB 262144              // fast: bf16 x [4096][1024] (8 MB)
#define OFF_HID_F 8650752          // fast: bf16 hidden [12288][2048] (48 MB)
#define OFF_W1T 58982400           // fast: bf16 W1 tiled (64 MB)
#define OFF_W2T 126091264          // fast: bf16 W2 tiled (64 MB)
#define NEED_FAST 193200128ull
#define OFF_HID_S 262144           // slow fallback: hidden at 256 KB
#define NEED_SLOW 50593792ull

__device__ __forceinline__ unsigned short f2bf(float f) {
    __bf16 h = (__bf16)f;
    return __builtin_bit_cast(unsigned short, h);
}

typedef const __attribute__((address_space(1))) unsigned int* as1_u32p;
typedef __attribute__((address_space(3))) unsigned int* as3_u32p;
__device__ __forceinline__ void gload16(const void* g, void* l) {
    __builtin_amdgcn_global_load_lds((as1_u32p)g, (as3_u32p)l, 16, 0, 0);
}

// ================= gating (+ optional x->bf16 convert) =================
__global__ void k_gating(const float* __restrict__ x, const float* __restrict__ gate,
                         int* __restrict__ topk_e, float* __restrict__ topk_w,
                         int* __restrict__ counts, unsigned short* __restrict__ xb) {
    const int t = blockIdx.x;
    const int l = threadIdx.x;
    const int e = l & 15, grp = l >> 4;
    const float* xr = x + (size_t)t * DDIM;
    double s = 0.0;
    const int d0 = grp * 256;
    for (int d = d0; d < d0 + 256; d += 4) {
        float4 xv = *(const float4*)(xr + d);
        s += (double)xv.x * (double)gate[(d + 0) * NEXP + e];
        s += (double)xv.y * (double)gate[(d + 1) * NEXP + e];
        s += (double)xv.z * (double)gate[(d + 2) * NEXP + e];
        s += (double)xv.w * (double)gate[(d + 3) * NEXP + e];
    }
    s += __shfl_xor(s, 16);
    s += __shfl_xor(s, 32);
    // all-lane coalesced x -> bf16 conversion (row is L1/L2 hot)
    if (xb) {
#pragma unroll
        for (int i = 0; i < 4; ++i) {
            int d = i * 256 + l * 4;
            float4 v = *(const float4*)(xr + d);
            ushort4 pk;
            pk.x = f2bf(v.x); pk.y = f2bf(v.y); pk.z = f2bf(v.z); pk.w = f2bf(v.w);
            *(ushort4*)&xb[(size_t)t * DDIM + d] = pk;
        }
    }
    // top-3 on double logits (softmax monotone); lowest index wins ties
    double cur = s;
    double lsel[3];
    int esel[3];
#pragma unroll
    for (int j = 0; j < 3; ++j) {
        double mx = cur;
#pragma unroll
        for (int off = 8; off >= 1; off >>= 1) {
            double o = __shfl_xor(mx, off);
            mx = (o > mx) ? o : mx;
        }
        unsigned long long b = __ballot(cur == mx);
        int sel = (__ffsll(b) - 1) & 15;
        esel[j] = sel;
        lsel[j] = mx;
        if (e == sel) cur = -1.0e300;
    }
    float w0 = 1.0f;
    float w1 = expf((float)(lsel[1] - lsel[0]));
    float w2 = expf((float)(lsel[2] - lsel[0]));
    float inv = 1.0f / (w0 + w1 + w2);
    if (l < 3) {
        float wv = (l == 0) ? w0 : (l == 1) ? w1 : w2;
        topk_e[t * 3 + l] = esel[l];
        topk_w[t * 3 + l] = wv * inv;
        atomicAdd(&counts[esel[l]], 1);
    }
}

__global__ void k_scan(int* __restrict__ meta) {
    if (threadIdx.x != 0) return;
    int* counts = meta;
    int* offs = meta + 16;
    int* cursor = meta + 48;
    int acc = 0;
    for (int e = 0; e < NEXP; ++e) {
        offs[e] = acc;
        cursor[e] = acc;
        acc += counts[e];
    }
    offs[NEXP] = acc;
    int nt = 0;
    for (int e = 0; e < NEXP; ++e)
        for (int r = offs[e]; r < offs[e + 1]; r += BM) {
            meta[128 + nt] = e;
            meta[256 + nt] = r;
            ++nt;
        }
    meta[64] = nt;
}

__global__ void k_scatter(const int* __restrict__ topk_e, const float* __restrict__ topk_w,
                          int* __restrict__ cursor, int* __restrict__ perm,
                          float* __restrict__ pw) {
    int t = blockIdx.x * blockDim.x + threadIdx.x;
    if (t >= NTOK) return;
#pragma unroll
    for (int j = 0; j < 3; ++j) {
        int e = topk_e[t * 3 + j];
        int pos = atomicAdd(&cursor[e], 1);
        perm[pos] = t;
        pw[pos] = topk_w[t * 3 + j];
    }
}

// ====== weight convert: W[e][K][N] fp32 -> tiled bf16, transposed + swizzled ======
// out tile (e,nt,kt): 128 rows (n) x 64 k = 16 KB; 1024 chunks of 16B.
// chunk (r,c) (c in [0,8)) holds k-chunk cs = c ^ (r&7):
//   elem i = bf16( W[e][kt*64 + 8*cs + i][nt*128 + r] )
template <int K, int N, int NTILES, int KTILES>
__global__ __launch_bounds__(256) void k_convW(const float* __restrict__ W,
                                               unsigned short* __restrict__ Wt) {
    __shared__ unsigned short Ls[64 * 132];
    const int b = blockIdx.x;
    const int kt = b % KTILES;
    const int nt = (b / KTILES) % NTILES;
    const int e = b / (KTILES * NTILES);
    const int tid = threadIdx.x;
#pragma unroll
    for (int q = 0; q < 8; ++q) {
        int idx = q * 256 + tid;  // 0..2047 : 64 k x 32 n-groups
        int k = idx >> 5, hg = idx & 31;
        const float* src = W + ((size_t)e * K + kt * 64 + k) * N + nt * 128 + hg * 4;
        float4 v = *(const float4*)src;
        ushort4 pk;
        pk.x = f2bf(v.x); pk.y = f2bf(v.y); pk.z = f2bf(v.z); pk.w = f2bf(v.w);
        *(ushort4*)&Ls[k * 132 + hg * 4] = pk;
    }
    __syncthreads();
    unsigned short* outb = Wt + (size_t)b * 8192;  // 16 KB tile
#pragma unroll
    for (int q = 0; q < 4; ++q) {
        int cidx = q * 256 + tid;  // 0..1023
        int r = cidx >> 3, c = cidx & 7;
        int cs = c ^ (r & 7);
        ushort8v v;
#pragma unroll
        for (int i = 0; i < 8; ++i) v[i] = Ls[(8 * cs + i) * 132 + r];
        *(ushort8v*)&outb[cidx * 8] = v;
    }
}

// ========== fast GEMMs: single-buffer 2-barrier loop, BK=64 ==========
// LDS image: row r = 128B (64 bf16 k-values) as 8 16B-chunks; chunk c holds
// k-chunk c^(r&7)  (read slot for k-chunk g at row r is g^(r&7); 16 rows map
// to 8 distinct slots x 4 banks = 32 banks, 2 lanes/bank = conflict-free).
__global__ __launch_bounds__(256) void k_gemm1_f(const unsigned short* __restrict__ xb,
                                                 const unsigned short* __restrict__ W1t,
                                                 const float* __restrict__ b1,
                                                 const int* __restrict__ meta,
                                                 const int* __restrict__ perm,
                                                 unsigned short* __restrict__ hidden) {
    const int b = blockIdx.x;
    const int wg = (b & 7) * 224 + (b >> 3);  // XCD-contiguous chunks (1792 = 8*224)
    const int mt = wg % MAXT1;
    const int y = wg / MAXT1;  // h-tile 0..15
    if (mt >= meta[64]) return;
    const int e = meta[128 + mt];
    const int r0 = meta[256 + mt];
    const int limit = meta[16 + e + 1] - r0;

    __shared__ unsigned short As_l[8192];  // 128 x 64
    __shared__ unsigned short Bs_l[8192];

    const int tid = threadIdx.x;
    const int lane = tid & 63, wave = tid >> 6;
    const int wr = wave >> 1, wc = wave & 1;

    // hoisted per-lane staging bases (4 chunks per matrix per K-step)
    size_t abase[4], bbase[4];
#pragma unroll
    for (int q = 0; q < 4; ++q) {
        int cidx = q * 256 + tid;
        int r = cidx >> 3, c = cidx & 7;
        int cs = c ^ (r & 7);
        int rr = r0 + r; if (rr > NPAIR - 1) rr = NPAIR - 1;
        abase[q] = (size_t)perm[rr] * (DDIM * 2) + (size_t)cs * 16;
        bbase[q] = (size_t)((e * 16 + y) * 16) * 16384 + (size_t)cidx * 16;
    }
    const char* xb_b = (const char*)xb;
    const char* w_b = (const char*)W1t;

    f32x4 acc[4][4];
#pragma unroll
    for (int i = 0; i < 4; ++i)
#pragma unroll
        for (int j = 0; j < 4; ++j) acc[i][j] = (f32x4){0.f, 0.f, 0.f, 0.f};

    for (int kt = 0; kt < DDIM / 64; ++kt) {
        __syncthreads();
#pragma unroll
        for (int q = 0; q < 4; ++q) {
            gload16(xb_b + abase[q] + (size_t)kt * 128, &As_l[(q * 256 + wave * 64) * 8]);
            gload16(w_b + bbase[q] + (size_t)kt * 16384, &Bs_l[(q * 256 + wave * 64) * 8]);
        }
        __syncthreads();
#pragma unroll
        for (int h = 0; h < 2; ++h) {
            bf16x8 af[4], bfr[4];
#pragma unroll
            for (int m = 0; m < 4; ++m) {
                int r = wr * 64 + m * 16 + (lane & 15);
                int c = (h * 4 + (lane >> 4)) ^ (r & 7);
                af[m] = *(const bf16x8*)&As_l[r * 64 + c * 8];
            }
#pragma unroll
            for (int n = 0; n < 4; ++n) {
                int r = wc * 64 + n * 16 + (lane & 15);
                int c = (h * 4 + (lane >> 4)) ^ (r & 7);
                bfr[n] = *(const bf16x8*)&Bs_l[r * 64 + c * 8];
            }
#pragma unroll
            for (int m = 0; m < 4; ++m)
#pragma unroll
                for (int n = 0; n < 4; ++n)
                    acc[m][n] = __builtin_amdgcn_mfma_f32_16x16x32_bf16(af[m], bfr[n], acc[m][n], 0, 0, 0);
        }
    }

    const int h0 = y * 128;
    float bias[4];
#pragma unroll
    for (int n = 0; n < 4; ++n)
        bias[n] = b1[(size_t)e * HDIM + h0 + wc * 64 + n * 16 + (lane & 15)];
#pragma unroll
    for (int m = 0; m < 4; ++m)
#pragma unroll
        for (int j = 0; j < 4; ++j) {
            int row = wr * 64 + m * 16 + (lane >> 4) * 4 + j;
            if (row < limit) {
                size_t base = (size_t)(r0 + row) * HDIM + h0;
#pragma unroll
                for (int n = 0; n < 4; ++n) {
                    int col = wc * 64 + n * 16 + (lane & 15);
                    float v = acc[m][n][j] + bias[n];
                    hidden[base + col] = f2bf(fmaxf(v, 0.f));
                }
            }
        }
}

// gemm2 with 2-way K-split: ks in {0,1}, each block does K=1024 of HDIM=2048.
__global__ __launch_bounds__(256) void k_gemm2_f(const unsigned short* __restrict__ hidden,
                                                 const unsigned short* __restrict__ W2t,
                                                 const float* __restrict__ b2,
                                                 const int* __restrict__ meta,
                                                 const int* __restrict__ perm,
                                                 const float* __restrict__ pw,
                                                 float* __restrict__ out) {
    const int b = blockIdx.x;
    const int wg = (b & 7) * 224 + (b >> 3);  // 1792 = 8*224
    const int mt = wg % MAXT2;
    const int rest = wg / MAXT2;  // 0..15
    const int y = rest & 7;       // d-tile 0..7
    const int ks = rest >> 3;     // K-split 0..1
    if (mt >= meta[64]) return;
    const int e = meta[128 + mt];
    const int r0 = meta[256 + mt];
    const int limit = meta[16 + e + 1] - r0;

    __shared__ unsigned short As_l[8192];
    __shared__ unsigned short Bs_l[8192];

    const int tid = threadIdx.x;
    const int lane = tid & 63, wave = tid >> 6;
    const int wr = wave >> 1, wc = wave & 1;

    size_t abase[4], bbase[4];
#pragma unroll
    for (int q = 0; q < 4; ++q) {
        int cidx = q * 256 + tid;
        int r = cidx >> 3, c = cidx & 7;
        int cs = c ^ (r & 7);
        int rr = r0 + r; if (rr > NPAIR - 1) rr = NPAIR - 1;
        abase[q] = (size_t)rr * (HDIM * 2) + (size_t)ks * 2048 + (size_t)cs * 16;
        bbase[q] = (size_t)((e * 8 + y) * 32 + ks * 16) * 16384 + (size_t)cidx * 16;
    }
    const char* h_b = (const char*)hidden;
    const char* w_b = (const char*)W2t;

    f32x4 acc[4][4];
#pragma unroll
    for (int i = 0; i < 4; ++i)
#pragma unroll
        for (int j = 0; j < 4; ++j) acc[i][j] = (f32x4){0.f, 0.f, 0.f, 0.f};

    for (int kt = 0; kt < 16; ++kt) {  // 1024 / 64
        __syncthreads();
#pragma unroll
        for (int q = 0; q < 4; ++q) {
            gload16(h_b + abase[q] + (size_t)kt * 128, &As_l[(q * 256 + wave * 64) * 8]);
            gload16(w_b + bbase[q] + (size_t)kt * 16384, &Bs_l[(q * 256 + wave * 64) * 8]);
        }
        __syncthreads();
#pragma unroll
        for (int h = 0; h < 2; ++h) {
            bf16x8 af[4], bfr[4];
#pragma unroll
            for (int m = 0; m < 4; ++m) {
                int r = wr * 64 + m * 16 + (lane & 15);
                int c = (h * 4 + (lane >> 4)) ^ (r & 7);
                af[m] = *(const bf16x8*)&As_l[r * 64 + c * 8];
            }
#pragma unroll
            for (int n = 0; n < 4; ++n) {
                int r = wc * 64 + n * 16 + (lane & 15);
                int c = (h * 4 + (lane >> 4)) ^ (r & 7);
                bfr[n] = *(const bf16x8*)&Bs_l[r * 64 + c * 8];
            }
#pragma unroll
            for (int m = 0; m < 4; ++m)
#pragma unroll
                for (int n = 0; n < 4; ++n)
                    acc[m][n] = __builtin_amdgcn_mfma_f32_16x16x32_bf16(af[m], bfr[n], acc[m][n], 0, 0, 0);
        }
    }

    const int n0 = y * 128;
    float bias[4];
#pragma unroll
    for (int n = 0; n < 4; ++n)
        bias[n] = b2[(size_t)e * DDIM + n0 + wc * 64 + n * 16 + (lane & 15)];
#pragma unroll
    for (int m = 0; m < 4; ++m)
#pragma unroll
        for (int j = 0; j < 4; ++j) {
            int row = wr * 64 + m * 16 + (lane >> 4) * 4 + j;
            if (row < limit) {
                int tok = perm[r0 + row];
                float w = pw[r0 + row];
#pragma unroll
                for (int n = 0; n < 4; ++n) {
                    int col = wc * 64 + n * 16 + (lane & 15);
                    float v = acc[m][n][j] + (ks == 0 ? bias[n] : 0.0f);
                    atomicAdd(&out[(size_t)tok * DDIM + n0 + col], v * w);
                }
            }
        }
}

// ================= slow fallback GEMMs (round-2, verified) =================
__global__ __launch_bounds__(256) void k_gemm1_s(const float* __restrict__ x,
                                                 const float* __restrict__ W1,
                                                 const float* __restrict__ b1,
                                                 const int* __restrict__ meta,
                                                 const int* __restrict__ perm,
                                                 unsigned short* __restrict__ hidden) {
    const int mt = blockIdx.x;
    if (mt >= meta[64]) return;
    const int e = meta[128 + mt];
    const int r0 = meta[256 + mt];
    const int limit = meta[16 + e + 1] - r0;
    const int h0 = blockIdx.y * 128;

    __shared__ unsigned short As[128][40];
    __shared__ unsigned short Bs[128][40];

    const int tid = threadIdx.x;
    const int lane = tid & 63, wave = tid >> 6;
    const int wr = wave >> 1, wc = wave & 1;
    const int arow = tid >> 1, ahalf = tid & 1;
    const float* aptr = nullptr;
    if (arow < limit) aptr = x + (size_t)perm[r0 + arow] * DDIM + ahalf * 16;

    f32x4 acc[4][4];
#pragma unroll
    for (int i = 0; i < 4; ++i)
#pragma unroll
        for (int j = 0; j < 4; ++j) acc[i][j] = (f32x4){0.f, 0.f, 0.f, 0.f};

    for (int k0 = 0; k0 < DDIM; k0 += 32) {
        __syncthreads();
#pragma unroll
        for (int i = 0; i < 4; ++i) {
            float4 v = make_float4(0.f, 0.f, 0.f, 0.f);
            if (aptr) v = *(const float4*)(aptr + k0 + i * 4);
            ushort4 pk;
            pk.x = f2bf(v.x); pk.y = f2bf(v.y); pk.z = f2bf(v.z); pk.w = f2bf(v.w);
            *(ushort4*)&As[arow][ahalf * 16 + i * 4] = pk;
        }
#pragma unroll
        for (int it = 0; it < 2; ++it) {
            int s = tid + it * 256;
            int kp = s >> 5, cg = s & 31;
            const float* bp = W1 + ((size_t)e * DDIM + k0 + 2 * kp) * HDIM + h0 + cg * 4;
            float4 v0 = *(const float4*)bp;
            float4 v1 = *(const float4*)(bp + HDIM);
#pragma unroll
            for (int c = 0; c < 4; ++c) {
                unsigned int u = ((unsigned)f2bf(((const float*)&v1)[c]) << 16) |
                                 f2bf(((const float*)&v0)[c]);
                *(unsigned int*)&Bs[cg * 4 + c][2 * kp] = u;
            }
        }
        __syncthreads();
        bf16x8 af[4], bfr[4];
#pragma unroll
        for (int m = 0; m < 4; ++m)
            af[m] = *(const bf16x8*)&As[wr * 64 + m * 16 + (lane & 15)][(lane >> 4) * 8];
#pragma unroll
        for (int n = 0; n < 4; ++n)
            bfr[n] = *(const bf16x8*)&Bs[wc * 64 + n * 16 + (lane & 15)][(lane >> 4) * 8];
#pragma unroll
        for (int m = 0; m < 4; ++m)
#pragma unroll
            for (int n = 0; n < 4; ++n)
                acc[m][n] = __builtin_amdgcn_mfma_f32_16x16x32_bf16(af[m], bfr[n], acc[m][n], 0, 0, 0);
    }

    float bias[4];
#pragma unroll
    for (int n = 0; n < 4; ++n)
        bias[n] = b1[(size_t)e * HDIM + h0 + wc * 64 + n * 16 + (lane & 15)];
#pragma unroll
    for (int m = 0; m < 4; ++m)
#pragma unroll
        for (int j = 0; j < 4; ++j) {
            int row = wr * 64 + m * 16 + (lane >> 4) * 4 + j;
            if (row < limit) {
                size_t base = (size_t)(r0 + row) * HDIM + h0;
#pragma unroll
                for (int n = 0; n < 4; ++n) {
                    int col = wc * 64 + n * 16 + (lane & 15);
                    float v = acc[m][n][j] + bias[n];
                    hidden[base + col] = f2bf(fmaxf(v, 0.f));
                }
            }
        }
}

__global__ __launch_bounds__(256) void k_gemm2_s(const unsigned short* __restrict__ hidden,
                                                 const float* __restrict__ W2,
                                                 const float* __restrict__ b2,
                                                 const int* __restrict__ meta,
                                                 const int* __restrict__ perm,
                                                 const float* __restrict__ pw,
                                                 float* __restrict__ out) {
    const int mt = blockIdx.x;
    if (mt >= meta[64]) return;
    const int e = meta[128 + mt];
    const int r0 = meta[256 + mt];
    const int limit = meta[16 + e + 1] - r0;
    const int n0 = blockIdx.y * 128;

    __shared__ unsigned short As[128][40];
    __shared__ unsigned short Bs[128][40];

    const int tid = threadIdx.x;
    const int lane = tid & 63, wave = tid >> 6;
    const int wr = wave >> 1, wc = wave & 1;
    const int arow = tid >> 1, ahalf = tid & 1;
    const unsigned short* aptr = nullptr;
    if (arow < limit) aptr = hidden + (size_t)(r0 + arow) * HDIM + ahalf * 16;

    f32x4 acc[4][4];
#pragma unroll
    for (int i = 0; i < 4; ++i)
#pragma unroll
        for (int j = 0; j < 4; ++j) acc[i][j] = (f32x4){0.f, 0.f, 0.f, 0.f};

    for (int k0 = 0; k0 < HDIM; k0 += 32) {
        __syncthreads();
#pragma unroll
        for (int i = 0; i < 2; ++i) {
            uint4 v = make_uint4(0u, 0u, 0u, 0u);
            if (aptr) v = *(const uint4*)(aptr + k0 + i * 8);
            *(uint4*)&As[arow][ahalf * 16 + i * 8] = v;
        }
#pragma unroll
        for (int it = 0; it < 2; ++it) {
            int s = tid + it * 256;
            int kp = s >> 5, cg = s & 31;
            const float* bp = W2 + ((size_t)e * HDIM + k0 + 2 * kp) * DDIM + n0 + cg * 4;
            float4 v0 = *(const float4*)bp;
            float4 v1 = *(const float4*)(bp + DDIM);
#pragma unroll
            for (int c = 0; c < 4; ++c) {
                unsigned int u = ((unsigned)f2bf(((const float*)&v1)[c]) << 16) |
                                 f2bf(((const float*)&v0)[c]);
                *(unsigned int*)&Bs[cg * 4 + c][2 * kp] = u;
            }
        }
        __syncthreads();
        bf16x8 af[4], bfr[4];
#pragma unroll
        for (int m = 0; m < 4; ++m)
            af[m] = *(const bf16x8*)&As[wr * 64 + m * 16 + (lane & 15)][(lane >> 4) * 8];
#pragma unroll
        for (int n = 0; n < 4; ++n)
            bfr[n] = *(const bf16x8*)&Bs[wc * 64 + n * 16 + (lane & 15)][(lane >> 4) * 8];
#pragma unroll
        for (int m = 0; m < 4; ++m)
#pragma unroll
            for (int n = 0; n < 4; ++n)
                acc[m][n] = __builtin_amdgcn_mfma_f32_16x16x32_bf16(af[m], bfr[n], acc[m][n], 0, 0, 0);
    }

    float bias[4];
#pragma unroll
    for (int n = 0; n < 4; ++n)
        bias[n] = b2[(size_t)e * DDIM + n0 + wc * 64 + n * 16 + (lane & 15)];
#pragma unroll
    for (int m = 0; m < 4; ++m)
#pragma unroll
        for (int j = 0; j < 4; ++j) {
            int row = wr * 64 + m * 16 + (lane >> 4) * 4 + j;
            if (row < limit) {
                int tok = perm[r0 + row];
                float w = pw[r0 + row];
#pragma unroll
                for (int n = 0; n < 4; ++n) {
                    int col = wc * 64 + n * 16 + (lane & 15);
                    float v = (acc[m][n][j] + bias[n]) * w;
                    atomicAdd(&out[(size_t)tok * DDIM + n0 + col], v);
                }
            }
        }
}

extern "C" void kernel_launch(void* const* d_in, const int* in_sizes, int n_in,
                              void* d_out, int out_size, void* d_ws, size_t ws_size,
                              hipStream_t stream) {
    const float* x = (const float*)d_in[0];
    const float* gate = (const float*)d_in[1];
    const float* W1 = (const float*)d_in[2];
    const float* b1 = (const float*)d_in[3];
    const float* W2 = (const float*)d_in[4];
    const float* b2 = (const float*)d_in[5];
    float* out = (float*)d_out;

    const bool fast = ws_size >= NEED_FAST;
    if (!fast && ws_size < NEED_SLOW) {
        fprintf(stderr, "SparseKMoE: ws_size %zu too small\n", ws_size);
        return;
    }
    char* ws = (char*)d_ws;
    int* meta = (int*)ws;
    int* topk_e = (int*)(ws + OFF_TOPKE);
    float* topk_w = (float*)(ws + OFF_TOPKW);
    int* perm = (int*)(ws + OFF_PERM);
    float* pw = (float*)(ws + OFF_PW);
    unsigned short* xb = (unsigned short*)(ws + OFF_XB);
    unsigned short* hidden = (unsigned short*)(ws + (fast ? OFF_HID_F : OFF_HID_S));
    unsigned short* W1t = (unsigned short*)(ws + OFF_W1T);
    unsigned short* W2t = (unsigned short*)(ws + OFF_W2T);

    hipMemsetAsync(meta, 0, 4096, stream);
    hipMemsetAsync(d_out, 0, (size_t)NTOK * DDIM * sizeof(float), stream);

    k_gating<<<NTOK, 64, 0, stream>>>(x, gate, topk_e, topk_w, meta, fast ? xb : nullptr);
    k_scan<<<1, 64, 0, stream>>>(meta);
    k_scatter<<<16, 256, 0, stream>>>(topk_e, topk_w, meta + 48, perm, pw);

    if (fast) {
        // BK=64 tiles: W1 -> 16 nt x 16 kt, W2 -> 8 nt x 32 kt (16 KB tiles)
        k_convW<DDIM, HDIM, 16, 16><<<NEXP * 16 * 16, 256, 0, stream>>>(W1, W1t);
        k_convW<HDIM, DDIM, 8, 32><<<NEXP * 8 * 32, 256, 0, stream>>>(W2, W2t);
        k_gemm1_f<<<MAXT1 * 16, 256, 0, stream>>>(xb, W1t, b1, meta, perm, hidden);
        k_gemm2_f<<<MAXT2 * 16, 256, 0, stream>>>(hidden, W2t, b2, meta, perm, pw, out);
    } else {
        dim3 g1(MAXT1, HDIM / 128);
        k_gemm1_s<<<g1, 256, 0, stream>>>(x, W1, b1, meta, perm, hidden);
        dim3 g2(MAXT2, DDIM / 128);
        k_gemm2_s<<<g2, 256, 0, stream>>>(hidden, W2, b2, meta, perm, pw, out);
    }
}